// Round 11
// baseline (939.260 us; speedup 1.0000x reference)
//
#include <hip/hip_runtime.h>

#define HW 65536

// ---- ws layout (float offsets) ----
constexpr int OFF_X    = 0;          // xT: 4b*16ci*256w*256h (transposed)
constexpr int OFF_CT   = 4194304;    // c transposed [b][g][w][h]
constexpr int OFF_MAX  = 8388608;
constexpr int OFF_SUM  = 12582912;
constexpr int P_K3  = 17039360;          // 256*8 softmax(scales2)
constexpr int P_K3S = P_K3  + 2048;      // shifted (j+4)%8
constexpr int P_K4  = P_K3S + 2048;      // 16*16 softmax(scales3)
constexpr int P_S1  = P_K4  + 256;       // softmax(scales1), 4
constexpr int P_BNS = P_S1  + 4;         // 16
constexpr int P_BNB = P_BNS + 16;        // 16
constexpr int P_WRI = P_BNB + 16;        // w_in  re-laid [ci][co] 1024
// conv weights packed fp16 co-pairs (uint32)
constexpr int P_WR0 = P_WRI + 1024;      // 128 u32  (1x1)
constexpr int P_WR1 = P_WR0 + 256;       // 1152 u32 (3x3)
constexpr int P_WR2 = P_WR1 + 2304;      // 3200 u32 (5x5)
constexpr int P_WR3 = P_WR2 + 6400;      // 6272 u32 (7x7)
constexpr int P_WRB = P_WR3 + 12544;     // 2304 fp32 (tail 3x3)
constexpr int P_K3H  = P_WRB + 2304;     // packed fp16 pairs: 16g*8p*8j = 1024 (uint32)
constexpr int P_K3SH = P_K3H + 1024;     // 1024

// clang-native packed fp16
typedef _Float16 hv2 __attribute__((ext_vector_type(2)));

__device__ __forceinline__ int h2i(hv2 v) { return __builtin_bit_cast(int, v); }
__device__ __forceinline__ hv2 i2h(int v) { return __builtin_bit_cast(hv2, v); }

// __builtin_amdgcn_cvt_pkrtz returns __fp16 ext_vector(2); bit-cast to hv2
__device__ __forceinline__ hv2 pkrtz(float a, float b) {
  return __builtin_bit_cast(hv2, __builtin_amdgcn_cvt_pkrtz(a, b));
}

// native packed fma (compiler folds uniform operands)
__device__ __forceinline__ hv2 pk_fma_n(hv2 a, hv2 b, hv2 c) {
#if __has_builtin(__builtin_elementwise_fma)
  return __builtin_elementwise_fma(a, b, c);
#else
  return a * b + c;
#endif
}

// guaranteed-packed fp16 ops (one VOP3P inst each) — R7 sort path
__device__ __forceinline__ hv2 pkmin(hv2 a, hv2 b) {
  hv2 d; asm("v_pk_min_f16 %0, %1, %2" : "=v"(d) : "v"(a), "v"(b)); return d;
}
__device__ __forceinline__ hv2 pkmax(hv2 a, hv2 b) {
  hv2 d; asm("v_pk_max_f16 %0, %1, %2" : "=v"(d) : "v"(a), "v"(b)); return d;
}
__device__ __forceinline__ hv2 pkmul(hv2 a, hv2 b) {
  hv2 d; asm("v_pk_mul_f16 %0, %1, %2" : "=v"(d) : "v"(a), "v"(b)); return d;
}
__device__ __forceinline__ hv2 pkfma(hv2 a, hv2 b, hv2 c) {
  hv2 d; asm("v_pk_fma_f16 %0, %1, %2, %3" : "=v"(d) : "v"(a), "v"(b), "v"(c)); return d;
}

// 32-bit select -> single v_cndmask_b32
__device__ __forceinline__ hv2 sel32(bool c, hv2 a, hv2 b) {
  return i2h(c ? h2i(a) : h2i(b));
}

// cross-lane xor: DPP quad_perm (VALU, ~4cy) for xor1/2; ds_swizzle for 4..16; bpermute for 32
template <int LMASK>
__device__ __forceinline__ int lane_xor_i(int x) {
  if constexpr (LMASK == 1) {
    return __builtin_amdgcn_mov_dpp(x, 0xB1, 0xF, 0xF, true);   // quad_perm [1,0,3,2]
  } else if constexpr (LMASK == 2) {
    return __builtin_amdgcn_mov_dpp(x, 0x4E, 0xF, 0xF, true);   // quad_perm [2,3,0,1]
  } else if constexpr (LMASK < 32) {
    return __builtin_amdgcn_ds_swizzle(x, (LMASK << 10) | 0x1F);
  } else {
    return __shfl_xor(x, LMASK, 64);
  }
}

__device__ __forceinline__ float sigmoid_fast(float x) {
  return __fdividef(1.0f, 1.0f + __expf(-x));
}

// ---------------- prep ----------------
__global__ void k_prep(const float* __restrict__ w_in, const float* __restrict__ w_c0,
                       const float* __restrict__ w_c1, const float* __restrict__ w_c2,
                       const float* __restrict__ w_c3, const float* __restrict__ w_base,
                       const float* __restrict__ scales1, const float* __restrict__ scales2,
                       const float* __restrict__ scales3, const float* __restrict__ bn_gamma,
                       const float* __restrict__ bn_beta, const float* __restrict__ bn_mean,
                       const float* __restrict__ bn_var, float* __restrict__ ws) {
  int tid = threadIdx.x;  // 256
  {
    const float* srow = scales2 + tid * 8;
    float v[8]; float mx = -1e30f;
    for (int j = 0; j < 8; j++) { v[j] = srow[j]; mx = fmaxf(mx, v[j]); }
    float s = 0.f;
    for (int j = 0; j < 8; j++) { v[j] = __expf(v[j] - mx); s += v[j]; }
    float inv = 1.0f / s;
    for (int j = 0; j < 8; j++) ws[P_K3 + tid * 8 + j] = v[j] * inv;
    for (int j = 0; j < 8; j++) ws[P_K3S + tid * 8 + j] = v[(j + 4) & 7] * inv;
  }
  if (tid < 16) {
    const float* srow = scales3 + tid * 16;
    float v[16]; float mx = -1e30f;
    for (int e = 0; e < 16; e++) { v[e] = srow[e]; mx = fmaxf(mx, v[e]); }
    float s = 0.f;
    for (int e = 0; e < 16; e++) { v[e] = __expf(v[e] - mx); s += v[e]; }
    float inv = 1.0f / s;
    for (int e = 0; e < 16; e++) ws[P_K4 + tid * 16 + e] = v[e] * inv;
  }
  if (tid == 0) {
    float v[4]; float mx = -1e30f;
    for (int i = 0; i < 4; i++) { v[i] = scales1[i]; mx = fmaxf(mx, v[i]); }
    float s = 0.f;
    for (int i = 0; i < 4; i++) { v[i] = __expf(v[i] - mx); s += v[i]; }
    for (int i = 0; i < 4; i++) ws[P_S1 + i] = v[i] / s;
  }
  if (tid < 16) {
    float rs = rsqrtf(bn_var[tid] + 1e-5f);
    float sc = bn_gamma[tid] * rs;
    ws[P_BNS + tid] = sc;
    ws[P_BNB + tid] = bn_beta[tid] - bn_mean[tid] * sc;
  }
  for (int i = tid; i < 1024; i += 256) { int ci = i >> 4, co = i & 15; ws[P_WRI + i] = w_in[co * 64 + ci]; }
  // packed fp16 co-pair conv weights
  {
    uint32_t* w0 = (uint32_t*)(ws + P_WR0);
    for (int i = tid; i < 128; i += 256) {
      int cp = i & 7, ci = i >> 3;
      hv2 wv;
      wv.x = (_Float16)w_c0[(2 * cp) * 16 + ci];
      wv.y = (_Float16)w_c0[(2 * cp + 1) * 16 + ci];
      w0[ci * 8 + cp] = __builtin_bit_cast(uint32_t, wv);
    }
    uint32_t* w1 = (uint32_t*)(ws + P_WR1);
    for (int i = tid; i < 1152; i += 256) {
      int cp = i & 7; int r = i >> 3; int kw = r % 3; r /= 3; int kh = r % 3; int ci = r / 3;
      hv2 wv;
      wv.x = (_Float16)w_c1[((2 * cp) * 16 + ci) * 9 + kh * 3 + kw];
      wv.y = (_Float16)w_c1[((2 * cp + 1) * 16 + ci) * 9 + kh * 3 + kw];
      w1[((ci * 3 + kh) * 3 + kw) * 8 + cp] = __builtin_bit_cast(uint32_t, wv);
    }
    uint32_t* w2 = (uint32_t*)(ws + P_WR2);
    for (int i = tid; i < 3200; i += 256) {
      int cp = i & 7; int r = i >> 3; int kw = r % 5; r /= 5; int kh = r % 5; int ci = r / 5;
      hv2 wv;
      wv.x = (_Float16)w_c2[((2 * cp) * 16 + ci) * 25 + kh * 5 + kw];
      wv.y = (_Float16)w_c2[((2 * cp + 1) * 16 + ci) * 25 + kh * 5 + kw];
      w2[((ci * 5 + kh) * 5 + kw) * 8 + cp] = __builtin_bit_cast(uint32_t, wv);
    }
    uint32_t* w3 = (uint32_t*)(ws + P_WR3);
    for (int i = tid; i < 6272; i += 256) {
      int cp = i & 7; int r = i >> 3; int kw = r % 7; r /= 7; int kh = r % 7; int ci = r / 7;
      hv2 wv;
      wv.x = (_Float16)w_c3[((2 * cp) * 16 + ci) * 49 + kh * 7 + kw];
      wv.y = (_Float16)w_c3[((2 * cp + 1) * 16 + ci) * 49 + kh * 7 + kw];
      w3[((ci * 7 + kh) * 7 + kw) * 8 + cp] = __builtin_bit_cast(uint32_t, wv);
    }
  }
  // wbr[((g*3+kw)*3+kh)*16+co] = w_base[co][g][kh][kw]  (fp32, tail conv)
  for (int i = tid; i < 2304; i += 256) {
    int co = i & 15; int r = i >> 4; int kh = r % 3; r /= 3; int kw = r % 3; int g = r / 3;
    ws[P_WRB + i] = w_base[((co * 16 + g) * 3 + kh) * 3 + kw];
  }
  __syncthreads();
  // packed fp16 k3 weights: idx -> g (idx>>6), p ((idx>>3)&7), j (idx&7)
  uint32_t* k3h  = (uint32_t*)(ws + P_K3H);
  uint32_t* k3sh = (uint32_t*)(ws + P_K3SH);
  for (int i = tid; i < 1024; i += 256) {
    int g = i >> 6, p = (i >> 3) & 7, j = i & 7;
    hv2 wv, wvs;
    wv.x  = (_Float16)ws[P_K3 + g * 128 + (2 * p) * 8 + j];
    wv.y  = (_Float16)ws[P_K3 + g * 128 + (2 * p + 1) * 8 + j];
    wvs.x = (_Float16)ws[P_K3S + g * 128 + (2 * p) * 8 + j];
    wvs.y = (_Float16)ws[P_K3S + g * 128 + (2 * p + 1) * 8 + j];
    k3h[i]  = __builtin_bit_cast(uint32_t, wv);
    k3sh[i] = __builtin_bit_cast(uint32_t, wvs);
  }
}

// ---------------- 1x1 conv 64->16, writes TRANSPOSED xT[b][ci][w][h] ----------------
__global__ __launch_bounds__(256) void k_in(const float* __restrict__ cen,
                                            const float* __restrict__ b_in,
                                            const float* __restrict__ ws,
                                            float* __restrict__ xT) {
  __shared__ float ldst[16 * 16 * 17];  // [co][tx(w)][ty(h)] padded
  int tid = threadIdx.x;
  int b = blockIdx.z;
  int hbase = blockIdx.y * 16, wbase = blockIdx.x * 16;
  int ty = tid >> 4, tx = tid & 15;  // h, w within tile
  const float* wri = ws + P_WRI;
  float acc[16];
#pragma unroll
  for (int co = 0; co < 16; co++) acc[co] = b_in[co];
  const float* cp = cen + b * 64 * HW + (hbase + ty) * 256 + wbase + tx;
#pragma unroll 4
  for (int ci = 0; ci < 64; ci++) {
    float v = cp[ci * HW];
#pragma unroll
    for (int co = 0; co < 16; co++) acc[co] = fmaf(wri[ci * 16 + co], v, acc[co]);
  }
#pragma unroll
  for (int co = 0; co < 16; co++) ldst[(co * 16 + tx) * 17 + ty] = acc[co];
  __syncthreads();
  int wy = tid >> 4, hx = tid & 15;  // w, h for transposed write
#pragma unroll
  for (int ci = 0; ci < 16; ci++) {
    xT[((b * 16 + ci) << 16) + (wbase + wy) * 256 + hbase + hx] =
        ldst[(ci * 16 + wy) * 17 + hx];
  }
}

// ---------------- branch conv (k x k, 16->16), register-column, packed-fp16 accum ----------------
template <int KS>
__global__ __launch_bounds__(256) void k_conv(const float* __restrict__ xT,
                                              const float* __restrict__ bias,
                                              const uint32_t* __restrict__ wrh,
                                              float* __restrict__ cT) {
  constexpr int P = KS / 2;
  const int tid = threadIdx.x;
  const int lane = tid & 63;
  const int wv = (blockIdx.x << 2) + (tid >> 6);  // 4096 waves: b(4) x w(256) x hseg(4)
  const int hseg = wv & 3;
  const int w = (wv >> 2) & 255;
  const int b = wv >> 10;
  const int hbase = hseg << 6;
  const float* xb = xT + ((b * 16) << 16);

  hv2 acc[8];
#pragma unroll
  for (int cp = 0; cp < 8; cp++) {
    hv2 bv;
    bv.x = (_Float16)bias[2 * cp];
    bv.y = (_Float16)bias[2 * cp + 1];
    acc[cp] = bv;
  }

#pragma unroll 2
  for (int ci = 0; ci < 16; ci++) {
#pragma unroll
    for (int kw = 0; kw < KS; kw++) {
      const int wc = w + kw - P;
      if ((unsigned)wc >= 256u) continue;  // zero-pad: wave-uniform skip
      const float* col = xb + (ci << 16) + (wc << 8);
      const int h0 = hbase + lane - P;
      float v0 = ((unsigned)h0 < 256u) ? col[h0] : 0.0f;
      float v1 = 0.0f;
      if (P > 0) {
        const int h1 = hbase + 64 - P + lane;
        v1 = (lane < 2 * P && (unsigned)h1 < 256u) ? col[h1] : 0.0f;
      }
#pragma unroll
      for (int kh = 0; kh < KS; kh++) {
        float tv;
        if (P == 0) {
          tv = v0;
        } else {
          const int s = lane + kh;  // tap source index in [0, 63+2P]
          float t0 = __shfl(v0, s & 63, 64);
          float t1 = __shfl(v1, (s - 64) & 63, 64);
          tv = (s < 64) ? t0 : t1;
        }
        const hv2 tp = pkrtz(tv, tv);
        const uint32_t* wp = wrh + ((ci * KS + kh) * KS + kw) * 8;
#pragma unroll
        for (int cp = 0; cp < 8; cp++)
          acc[cp] = pk_fma_n(i2h((int)wp[cp]), tp, acc[cp]);
      }
    }
  }
  float* o = cT + ((b * 16) << 16) + (w << 8) + hbase + lane;
#pragma unroll
  for (int cp = 0; cp < 8; cp++) {
    o[(2 * cp) << 16] = (float)acc[cp].x;
    o[(2 * cp + 1) << 16] = (float)acc[cp].y;
  }
}

// ---------------- packed-fp16 bitonic sort of 256 values: 64 lanes x 4 regs ----------------
__device__ __forceinline__ void ce_pair_h(hv2& a, hv2& b, bool up) {
  hv2 lo = pkmin(a, b);
  hv2 hi = pkmax(a, b);
  a = sel32(up, lo, hi);
  b = sel32(up, hi, lo);
}

template <int SIZE, int DIST>
__device__ __forceinline__ void stage_x_h(hv2 v[4], int i0) {
  const bool keepmin = (((i0 & DIST) == 0) == ((i0 & SIZE) == 0));
#pragma unroll
  for (int r = 0; r < 4; r++) {
    hv2 pv = i2h(lane_xor_i<(DIST >> 2)>(h2i(v[r])));
    v[r] = sel32(keepmin, pkmin(v[r], pv), pkmax(v[r], pv));
  }
}

template <int SIZE>
__device__ __forceinline__ void stage_d21_h(hv2 v[4], int i0) {
  bool up = ((i0 & SIZE) == 0);
  ce_pair_h(v[0], v[2], up); ce_pair_h(v[1], v[3], up);
  ce_pair_h(v[0], v[1], up); ce_pair_h(v[2], v[3], up);
}

__device__ __forceinline__ void sort256h(hv2 v[4], int lane) {
  int i0 = lane << 2;
  ce_pair_h(v[0], v[1], true); ce_pair_h(v[2], v[3], false);   // size 2
  stage_d21_h<4>(v, i0);                                       // size 4
  stage_x_h<8, 4>(v, i0); stage_d21_h<8>(v, i0);
  stage_x_h<16, 8>(v, i0); stage_x_h<16, 4>(v, i0); stage_d21_h<16>(v, i0);
  stage_x_h<32, 16>(v, i0); stage_x_h<32, 8>(v, i0); stage_x_h<32, 4>(v, i0); stage_d21_h<32>(v, i0);
  stage_x_h<64, 32>(v, i0); stage_x_h<64, 16>(v, i0); stage_x_h<64, 8>(v, i0); stage_x_h<64, 4>(v, i0); stage_d21_h<64>(v, i0);
  stage_x_h<128, 64>(v, i0); stage_x_h<128, 32>(v, i0); stage_x_h<128, 16>(v, i0); stage_x_h<128, 8>(v, i0); stage_x_h<128, 4>(v, i0); stage_d21_h<128>(v, i0);
  stage_x_h<256, 128>(v, i0); stage_x_h<256, 64>(v, i0); stage_x_h<256, 32>(v, i0); stage_x_h<256, 16>(v, i0); stage_x_h<256, 8>(v, i0); stage_x_h<256, 4>(v, i0); stage_d21_h<256>(v, i0);
}

// ---------------- fused diff/k3/mul/sort/silu/k4 + branch max/sum accum ----------------
template <int DIL>
__global__ __launch_bounds__(256) void k_branch(const float* __restrict__ cT,
                                                const float* __restrict__ ws,
                                                float* __restrict__ maxb,
                                                float* __restrict__ sumb,
                                                int initFlag) {
  const int tid = threadIdx.x;
  const int lane = tid & 63;
  // wave-uniform task id via readfirstlane -> scalar addressing + s_load weights
  const int wid = __builtin_amdgcn_readfirstlane(tid >> 6);
  const int wv = (blockIdx.x << 2) + wid;
  const int w = wv & 255;
  const int g = (wv >> 8) & 15;
  const int b = wv >> 12;
  const float* base = cT + ((b * 16 + g) << 16);

  float vals[3][3][4];
#pragma unroll
  for (int wi = 0; wi < 3; ++wi) {
    const int wc = w + (wi - 1) * DIL;
    const bool wok = ((unsigned)wc < 256u);
    const float* col = base + (wok ? wc : 0) * 256;
#pragma unroll
    for (int si = 0; si < 3; ++si) {
#pragma unroll
      for (int r = 0; r < 4; ++r) {
        const int h = lane + (r << 6) + (si - 1) * DIL;
        const bool ok = wok && ((unsigned)h < 256u);
        vals[wi][si][r] = ok ? col[h] : 0.0f;
      }
    }
  }
  // directional differences (fp32), then broadcast-pack to fp16x2
  hv2 ddh[8][4];
#pragma unroll
  for (int r = 0; r < 4; ++r) {
    const float c0 = vals[1][1][r];
    float d0 = c0 - vals[0][0][r];  // (h-d, w-d)
    float d1 = c0 - vals[1][0][r];  // (h-d, w)
    float d2 = c0 - vals[2][0][r];  // (h-d, w+d)
    float d3 = c0 - vals[0][1][r];  // (h,   w-d)
    float d4 = c0 - vals[2][2][r];  // (h+d, w+d)
    float d5 = c0 - vals[1][2][r];  // (h+d, w)
    float d6 = c0 - vals[0][2][r];  // (h+d, w-d)
    float d7 = c0 - vals[2][1][r];  // (h,   w+d)
    ddh[0][r] = pkrtz(d0, d0);
    ddh[1][r] = pkrtz(d1, d1);
    ddh[2][r] = pkrtz(d2, d2);
    ddh[3][r] = pkrtz(d3, d3);
    ddh[4][r] = pkrtz(d4, d4);
    ddh[5][r] = pkrtz(d5, d5);
    ddh[6][r] = pkrtz(d6, d6);
    ddh[7][r] = pkrtz(d7, d7);
  }
  float out[4] = {0.f, 0.f, 0.f, 0.f};
  const uint32_t* k3h  = (const uint32_t*)(ws + P_K3H)  + g * 64;
  const uint32_t* k3sh = (const uint32_t*)(ws + P_K3SH) + g * 64;
  const float* k4p = ws + P_K4 + g * 16;
#pragma unroll 1
  for (int p = 0; p < 8; ++p) {
    hv2 t[4];
    hv2 wk3[8], wk3s[8];
#pragma unroll
    for (int j = 0; j < 8; ++j) {
      wk3[j]  = i2h((int)k3h[p * 8 + j]);
      wk3s[j] = i2h((int)k3sh[p * 8 + j]);
    }
#pragma unroll
    for (int r = 0; r < 4; ++r) {
      hv2 o1 = pkmul(wk3[0], ddh[0][r]);
      hv2 o2 = pkmul(wk3s[0], ddh[0][r]);
#pragma unroll
      for (int j = 1; j < 8; ++j) {
        o1 = pkfma(wk3[j], ddh[j][r], o1);
        o2 = pkfma(wk3s[j], ddh[j][r], o2);
      }
      t[r] = pkmul(o1, o2);
    }
    sort256h(t, lane);
    const float k4a = k4p[2 * p], k4b = k4p[2 * p + 1];
#pragma unroll
    for (int r = 0; r < 4; ++r) {
      const float va = (float)t[r].x;
      const float vb = (float)t[r].y;
      out[r] = fmaf(k4a, va * sigmoid_fast(va), out[r]);
      out[r] = fmaf(k4b, vb * sigmoid_fast(vb), out[r]);
    }
  }
  const int obase = (((b * 16 + g) << 8) + w) * 256 + (lane << 2);
  float4 o4 = make_float4(out[0], out[1], out[2], out[3]);
  float4* mp = (float4*)(maxb + obase);
  float4* sp = (float4*)(sumb + obase);
  if (initFlag) {
    *mp = o4;
    *sp = o4;
  } else {
    float4 m = *mp;
    m.x = fmaxf(m.x, o4.x); m.y = fmaxf(m.y, o4.y);
    m.z = fmaxf(m.z, o4.z); m.w = fmaxf(m.w, o4.w);
    *mp = m;
    float4 s = *sp;
    s.x += o4.x; s.y += o4.y; s.z += o4.z; s.w += o4.w;
    *sp = s;
  }
}

// ---------------- combine + 3x3 conv + BN + SiLU + 1x1 + sigmoid + GATE (fused tail) ----------------
__global__ __launch_bounds__(256) void k_tail(const float* __restrict__ maxb,
                                              const float* __restrict__ sumb,
                                              const float* __restrict__ ws,
                                              const float* __restrict__ cen,
                                              const float* __restrict__ mas,
                                              const float* __restrict__ w_out,
                                              const float* __restrict__ b_out,
                                              float* __restrict__ out) {
  __shared__ float lds[16 * 18 * 18];
  __shared__ float ldsf[256];
  int tid = threadIdx.x;
  int b = blockIdx.z;
  int wbase = blockIdx.x * 16, hbase = blockIdx.y * 16;
  const float* mb = maxb + (b * 16) * HW;  // [g][w][h]
  const float* sb = sumb + (b * 16) * HW;
  for (int i = tid; i < 16 * 18 * 18; i += 256) {
    int g = i / 324; int r = i % 324; int xx = r / 18, yy = r % 18;
    int wq = wbase + xx - 1, hq = hbase + yy - 1;
    float v = 0.0f;
    if (wq >= 0 && wq < 256 && hq >= 0 && hq < 256) {
      int idx = g * HW + wq * 256 + hq;
      v = mb[idx] + 0.25f * sb[idx];
    }
    lds[i] = v;
  }
  __syncthreads();
  int xw = tid >> 4, yh = tid & 15;  // pixel (w = wbase+xw, h = hbase+yh)
  float acc[16] = {0.f, 0.f, 0.f, 0.f, 0.f, 0.f, 0.f, 0.f,
                   0.f, 0.f, 0.f, 0.f, 0.f, 0.f, 0.f, 0.f};
  for (int g = 0; g < 16; g++) {
#pragma unroll
    for (int kw = 0; kw < 3; kw++) {
#pragma unroll
      for (int kh = 0; kh < 3; kh++) {
        float v = lds[g * 324 + (xw + kw) * 18 + (yh + kh)];
        const float* wp = ws + P_WRB + ((g * 3 + kw) * 3 + kh) * 16;
#pragma unroll
        for (int co = 0; co < 16; co++) acc[co] = fmaf(wp[co], v, acc[co]);
      }
    }
  }
  float mo = b_out[0];
#pragma unroll
  for (int co = 0; co < 16; co++) {
    float z = acc[co] * ws[P_BNS + co] + ws[P_BNB + co];
    float sl = z * sigmoid_fast(z);
    mo = fmaf(w_out[co], sl, mo);
  }
  float mk = sigmoid_fast(mo);
  ldsf[yh * 16 + xw] = mk;
  __syncthreads();
  // compute gate factor f per pixel under coalesced (yy,xx) mapping
  {
    int yy = tid >> 4, xx = tid & 15;
    float mkv = ldsf[yy * 16 + xx];
    float m = sigmoid_fast(mas[b * HW + (hbase + yy) * 256 + wbase + xx]);
    float s0 = ws[P_S1], s1 = ws[P_S1 + 1], s2 = ws[P_S1 + 2], s3 = ws[P_S1 + 3];
    float f = mkv * m * s0 + m * s1 + s2 * mkv + s3;
    ldsf[yy * 16 + xx] = f;  // each thread overwrites the slot it just read
  }
  __syncthreads();
  // gate all 64 cen channels, float4 over w: flat = it*256+tid -> ci(6b), yy(4b), wq(2b)
  const float* cb = cen + b * 64 * HW;
  float* ob = out + b * 64 * HW;
#pragma unroll 4
  for (int it = 0; it < 16; ++it) {
    int flat = it * 256 + tid;
    int ci = flat >> 6;
    int rr = flat & 63;
    int yy = rr >> 2, wq = rr & 3;
    const float* fr = &ldsf[yy * 16 + wq * 4];
    float4 f4 = make_float4(fr[0], fr[1], fr[2], fr[3]);
    int addr = ci * HW + (hbase + yy) * 256 + wbase + wq * 4;
    const float4 c4 = *(const float4*)(cb + addr);
    float4 o4;
    o4.x = c4.x * f4.x; o4.y = c4.y * f4.y; o4.z = c4.z * f4.z; o4.w = c4.w * f4.w;
    *(float4*)(ob + addr) = o4;
  }
}

extern "C" void kernel_launch(void* const* d_in, const int* in_sizes, int n_in,
                              void* d_out, int out_size, void* d_ws, size_t ws_size,
                              hipStream_t stream) {
  (void)in_sizes; (void)n_in; (void)out_size; (void)ws_size;
  const float* cen = (const float*)d_in[0];
  const float* mas = (const float*)d_in[1];
  const float* w_in = (const float*)d_in[2];
  const float* b_in = (const float*)d_in[3];
  const float* w_c0 = (const float*)d_in[4];
  const float* b_c0 = (const float*)d_in[5];
  const float* w_c1 = (const float*)d_in[6];
  const float* b_c1 = (const float*)d_in[7];
  const float* w_c2 = (const float*)d_in[8];
  const float* b_c2 = (const float*)d_in[9];
  const float* w_c3 = (const float*)d_in[10];
  const float* b_c3 = (const float*)d_in[11];
  const float* scales1 = (const float*)d_in[12];
  const float* scales2 = (const float*)d_in[13];
  const float* scales3 = (const float*)d_in[14];
  const float* w_base = (const float*)d_in[15];
  const float* bn_gamma = (const float*)d_in[16];
  const float* bn_beta = (const float*)d_in[17];
  const float* bn_mean = (const float*)d_in[18];
  const float* bn_var = (const float*)d_in[19];
  const float* w_out = (const float*)d_in[20];
  const float* b_out = (const float*)d_in[21];
  float* ws = (float*)d_ws;
  float* out = (float*)d_out;

  float* xT = ws + OFF_X;
  float* cT = ws + OFF_CT;
  float* maxb = ws + OFF_MAX;
  float* sumb = ws + OFF_SUM;

  k_prep<<<1, 256, 0, stream>>>(w_in, w_c0, w_c1, w_c2, w_c3, w_base, scales1, scales2,
                                scales3, bn_gamma, bn_beta, bn_mean, bn_var, ws);
  k_in<<<dim3(16, 16, 4), 256, 0, stream>>>(cen, b_in, ws, xT);

  k_conv<1><<<1024, 256, 0, stream>>>(xT, b_c0, (const uint32_t*)(ws + P_WR0), cT);
  k_branch<1><<<4096, 256, 0, stream>>>(cT, ws, maxb, sumb, 1);
  k_conv<3><<<1024, 256, 0, stream>>>(xT, b_c1, (const uint32_t*)(ws + P_WR1), cT);
  k_branch<3><<<4096, 256, 0, stream>>>(cT, ws, maxb, sumb, 0);
  k_conv<5><<<1024, 256, 0, stream>>>(xT, b_c2, (const uint32_t*)(ws + P_WR2), cT);
  k_branch<5><<<4096, 256, 0, stream>>>(cT, ws, maxb, sumb, 0);
  k_conv<7><<<1024, 256, 0, stream>>>(xT, b_c3, (const uint32_t*)(ws + P_WR3), cT);
  k_branch<7><<<4096, 256, 0, stream>>>(cT, ws, maxb, sumb, 0);

  k_tail<<<dim3(16, 16, 4), 256, 0, stream>>>(maxb, sumb, ws, cen, mas, w_out, b_out, out);
}

// Round 12
// 884.885 us; speedup vs baseline: 1.0614x; 1.0614x over previous
//
#include <hip/hip_runtime.h>

#define HW 65536

// ---- ws layout (float offsets) ----
constexpr int OFF_X    = 0;          // xT: 4b*16ci*256w*256h (transposed)
constexpr int OFF_CT   = 4194304;    // c transposed [b][g][w][h]
constexpr int OFF_MAX  = 8388608;
constexpr int OFF_SUM  = 12582912;
constexpr int P_K3  = 17039360;          // 256*8 softmax(scales2)
constexpr int P_K3S = P_K3  + 2048;      // (unused now)
constexpr int P_K4  = P_K3S + 2048;      // 16*16 softmax(scales3)
constexpr int P_S1  = P_K4  + 256;       // softmax(scales1), 4
constexpr int P_BNS = P_S1  + 4;         // 16
constexpr int P_BNB = P_BNS + 16;        // 16
constexpr int P_WRI = P_BNB + 16;        // w_in  re-laid [ci][co] 1024
// conv weights packed fp16 co-pairs (uint32)
constexpr int P_WR0 = P_WRI + 1024;      // 128 u32  (1x1)
constexpr int P_WR1 = P_WR0 + 256;       // 1152 u32 (3x3)
constexpr int P_WR2 = P_WR1 + 2304;      // 3200 u32 (5x5)
constexpr int P_WR3 = P_WR2 + 6400;      // 6272 u32 (7x7)
constexpr int P_WRB = P_WR3 + 12544;     // 2304 fp32 (tail 3x3)
constexpr int P_K3U = P_WRB + 2304;      // packed fp16 (k3[j]+k3[j+4])/2: 16g*8p*4j = 512 u32
constexpr int P_K3V = P_K3U + 512;       // packed fp16 (k3[j]-k3[j+4])/2: 512 u32

// clang-native packed fp16
typedef _Float16 hv2 __attribute__((ext_vector_type(2)));

__device__ __forceinline__ int h2i(hv2 v) { return __builtin_bit_cast(int, v); }
__device__ __forceinline__ hv2 i2h(int v) { return __builtin_bit_cast(hv2, v); }

// __builtin_amdgcn_cvt_pkrtz returns __fp16 ext_vector(2); bit-cast to hv2
__device__ __forceinline__ hv2 pkrtz(float a, float b) {
  return __builtin_bit_cast(hv2, __builtin_amdgcn_cvt_pkrtz(a, b));
}

// native packed fma (compiler folds uniform operands)
__device__ __forceinline__ hv2 pk_fma_n(hv2 a, hv2 b, hv2 c) {
#if __has_builtin(__builtin_elementwise_fma)
  return __builtin_elementwise_fma(a, b, c);
#else
  return a * b + c;
#endif
}

// guaranteed-packed fp16 ops (one VOP3P inst each)
__device__ __forceinline__ hv2 pkmin(hv2 a, hv2 b) {
  hv2 d; asm("v_pk_min_f16 %0, %1, %2" : "=v"(d) : "v"(a), "v"(b)); return d;
}
__device__ __forceinline__ hv2 pkmax(hv2 a, hv2 b) {
  hv2 d; asm("v_pk_max_f16 %0, %1, %2" : "=v"(d) : "v"(a), "v"(b)); return d;
}
__device__ __forceinline__ hv2 pkmul(hv2 a, hv2 b) {
  hv2 d; asm("v_pk_mul_f16 %0, %1, %2" : "=v"(d) : "v"(a), "v"(b)); return d;
}
__device__ __forceinline__ hv2 pkfma(hv2 a, hv2 b, hv2 c) {
  hv2 d; asm("v_pk_fma_f16 %0, %1, %2, %3" : "=v"(d) : "v"(a), "v"(b), "v"(c)); return d;
}

// 32-bit select -> single v_cndmask_b32
__device__ __forceinline__ hv2 sel32(bool c, hv2 a, hv2 b) {
  return i2h(c ? h2i(a) : h2i(b));
}

// cross-lane xor: ds_swizzle (DS pipe, free when VALU-bound) for <32, shfl for 32
template <int LMASK>
__device__ __forceinline__ int lane_xor_i(int x) {
  if constexpr (LMASK < 32) {
    return __builtin_amdgcn_ds_swizzle(x, (LMASK << 10) | 0x1F);
  } else {
    return __shfl_xor(x, LMASK, 64);
  }
}

__device__ __forceinline__ float sigmoid_fast(float x) {
  return __fdividef(1.0f, 1.0f + __expf(-x));
}

// ---------------- prep ----------------
__global__ void k_prep(const float* __restrict__ w_in, const float* __restrict__ w_c0,
                       const float* __restrict__ w_c1, const float* __restrict__ w_c2,
                       const float* __restrict__ w_c3, const float* __restrict__ w_base,
                       const float* __restrict__ scales1, const float* __restrict__ scales2,
                       const float* __restrict__ scales3, const float* __restrict__ bn_gamma,
                       const float* __restrict__ bn_beta, const float* __restrict__ bn_mean,
                       const float* __restrict__ bn_var, float* __restrict__ ws) {
  int tid = threadIdx.x;  // 256
  {
    const float* srow = scales2 + tid * 8;
    float v[8]; float mx = -1e30f;
    for (int j = 0; j < 8; j++) { v[j] = srow[j]; mx = fmaxf(mx, v[j]); }
    float s = 0.f;
    for (int j = 0; j < 8; j++) { v[j] = __expf(v[j] - mx); s += v[j]; }
    float inv = 1.0f / s;
    for (int j = 0; j < 8; j++) ws[P_K3 + tid * 8 + j] = v[j] * inv;
  }
  if (tid < 16) {
    const float* srow = scales3 + tid * 16;
    float v[16]; float mx = -1e30f;
    for (int e = 0; e < 16; e++) { v[e] = srow[e]; mx = fmaxf(mx, v[e]); }
    float s = 0.f;
    for (int e = 0; e < 16; e++) { v[e] = __expf(v[e] - mx); s += v[e]; }
    float inv = 1.0f / s;
    for (int e = 0; e < 16; e++) ws[P_K4 + tid * 16 + e] = v[e] * inv;
  }
  if (tid == 0) {
    float v[4]; float mx = -1e30f;
    for (int i = 0; i < 4; i++) { v[i] = scales1[i]; mx = fmaxf(mx, v[i]); }
    float s = 0.f;
    for (int i = 0; i < 4; i++) { v[i] = __expf(v[i] - mx); s += v[i]; }
    for (int i = 0; i < 4; i++) ws[P_S1 + i] = v[i] / s;
  }
  if (tid < 16) {
    float rs = rsqrtf(bn_var[tid] + 1e-5f);
    float sc = bn_gamma[tid] * rs;
    ws[P_BNS + tid] = sc;
    ws[P_BNB + tid] = bn_beta[tid] - bn_mean[tid] * sc;
  }
  for (int i = tid; i < 1024; i += 256) { int ci = i >> 4, co = i & 15; ws[P_WRI + i] = w_in[co * 64 + ci]; }
  // packed fp16 co-pair conv weights
  {
    uint32_t* w0 = (uint32_t*)(ws + P_WR0);
    for (int i = tid; i < 128; i += 256) {
      int cp = i & 7, ci = i >> 3;
      hv2 wv;
      wv.x = (_Float16)w_c0[(2 * cp) * 16 + ci];
      wv.y = (_Float16)w_c0[(2 * cp + 1) * 16 + ci];
      w0[ci * 8 + cp] = __builtin_bit_cast(uint32_t, wv);
    }
    uint32_t* w1 = (uint32_t*)(ws + P_WR1);
    for (int i = tid; i < 1152; i += 256) {
      int cp = i & 7; int r = i >> 3; int kw = r % 3; r /= 3; int kh = r % 3; int ci = r / 3;
      hv2 wv;
      wv.x = (_Float16)w_c1[((2 * cp) * 16 + ci) * 9 + kh * 3 + kw];
      wv.y = (_Float16)w_c1[((2 * cp + 1) * 16 + ci) * 9 + kh * 3 + kw];
      w1[((ci * 3 + kh) * 3 + kw) * 8 + cp] = __builtin_bit_cast(uint32_t, wv);
    }
    uint32_t* w2 = (uint32_t*)(ws + P_WR2);
    for (int i = tid; i < 3200; i += 256) {
      int cp = i & 7; int r = i >> 3; int kw = r % 5; r /= 5; int kh = r % 5; int ci = r / 5;
      hv2 wv;
      wv.x = (_Float16)w_c2[((2 * cp) * 16 + ci) * 25 + kh * 5 + kw];
      wv.y = (_Float16)w_c2[((2 * cp + 1) * 16 + ci) * 25 + kh * 5 + kw];
      w2[((ci * 5 + kh) * 5 + kw) * 8 + cp] = __builtin_bit_cast(uint32_t, wv);
    }
    uint32_t* w3 = (uint32_t*)(ws + P_WR3);
    for (int i = tid; i < 6272; i += 256) {
      int cp = i & 7; int r = i >> 3; int kw = r % 7; r /= 7; int kh = r % 7; int ci = r / 7;
      hv2 wv;
      wv.x = (_Float16)w_c3[((2 * cp) * 16 + ci) * 49 + kh * 7 + kw];
      wv.y = (_Float16)w_c3[((2 * cp + 1) * 16 + ci) * 49 + kh * 7 + kw];
      w3[((ci * 7 + kh) * 7 + kw) * 8 + cp] = __builtin_bit_cast(uint32_t, wv);
    }
  }
  // wbr[((g*3+kw)*3+kh)*16+co] = w_base[co][g][kh][kw]  (fp32, tail conv)
  for (int i = tid; i < 2304; i += 256) {
    int co = i & 15; int r = i >> 4; int kh = r % 3; r /= 3; int kw = r % 3; int g = r / 3;
    ws[P_WRB + i] = w_base[((co * 16 + g) * 3 + kh) * 3 + kw];
  }
  __syncthreads();
  // factored k3 weights: k3u = (k3[j]+k3[j+4])/2, k3v = (k3[j]-k3[j+4])/2, j=0..3
  // packed per e-pair (2p, 2p+1): idx i -> g(i>>5), p((i>>2)&7), j(i&3)
  uint32_t* k3u = (uint32_t*)(ws + P_K3U);
  uint32_t* k3v = (uint32_t*)(ws + P_K3V);
  for (int i = tid; i < 512; i += 256) {
    int g = i >> 5, p = (i >> 2) & 7, j = i & 3;
    const float* r0 = ws + P_K3 + g * 128 + (2 * p) * 8;
    const float* r1 = ws + P_K3 + g * 128 + (2 * p + 1) * 8;
    hv2 wu, wv;
    wu.x = (_Float16)((r0[j] + r0[j + 4]) * 0.5f);
    wu.y = (_Float16)((r1[j] + r1[j + 4]) * 0.5f);
    wv.x = (_Float16)((r0[j] - r0[j + 4]) * 0.5f);
    wv.y = (_Float16)((r1[j] - r1[j + 4]) * 0.5f);
    k3u[i] = __builtin_bit_cast(uint32_t, wu);
    k3v[i] = __builtin_bit_cast(uint32_t, wv);
  }
}

// ---------------- 1x1 conv 64->16, writes TRANSPOSED xT[b][ci][w][h] ----------------
__global__ __launch_bounds__(256) void k_in(const float* __restrict__ cen,
                                            const float* __restrict__ b_in,
                                            const float* __restrict__ ws,
                                            float* __restrict__ xT) {
  __shared__ float ldst[16 * 16 * 17];  // [co][tx(w)][ty(h)] padded
  int tid = threadIdx.x;
  int b = blockIdx.z;
  int hbase = blockIdx.y * 16, wbase = blockIdx.x * 16;
  int ty = tid >> 4, tx = tid & 15;  // h, w within tile
  const float* wri = ws + P_WRI;
  float acc[16];
#pragma unroll
  for (int co = 0; co < 16; co++) acc[co] = b_in[co];
  const float* cp = cen + b * 64 * HW + (hbase + ty) * 256 + wbase + tx;
#pragma unroll 4
  for (int ci = 0; ci < 64; ci++) {
    float v = cp[ci * HW];
#pragma unroll
    for (int co = 0; co < 16; co++) acc[co] = fmaf(wri[ci * 16 + co], v, acc[co]);
  }
#pragma unroll
  for (int co = 0; co < 16; co++) ldst[(co * 16 + tx) * 17 + ty] = acc[co];
  __syncthreads();
  int wy = tid >> 4, hx = tid & 15;  // w, h for transposed write
#pragma unroll
  for (int ci = 0; ci < 16; ci++) {
    xT[((b * 16 + ci) << 16) + (wbase + wy) * 256 + hbase + hx] =
        ldst[(ci * 16 + wy) * 17 + hx];
  }
}

// ---------------- branch conv (k x k, 16->16), register-column, packed-fp16 accum ----------------
template <int KS>
__global__ __launch_bounds__(256) void k_conv(const float* __restrict__ xT,
                                              const float* __restrict__ bias,
                                              const uint32_t* __restrict__ wrh,
                                              float* __restrict__ cT) {
  constexpr int P = KS / 2;
  const int tid = threadIdx.x;
  const int lane = tid & 63;
  const int wv = (blockIdx.x << 2) + (tid >> 6);  // 4096 waves: b(4) x w(256) x hseg(4)
  const int hseg = wv & 3;
  const int w = (wv >> 2) & 255;
  const int b = wv >> 10;
  const int hbase = hseg << 6;
  const float* xb = xT + ((b * 16) << 16);

  hv2 acc[8];
#pragma unroll
  for (int cp = 0; cp < 8; cp++) {
    hv2 bv;
    bv.x = (_Float16)bias[2 * cp];
    bv.y = (_Float16)bias[2 * cp + 1];
    acc[cp] = bv;
  }

#pragma unroll 2
  for (int ci = 0; ci < 16; ci++) {
#pragma unroll
    for (int kw = 0; kw < KS; kw++) {
      const int wc = w + kw - P;
      if ((unsigned)wc >= 256u) continue;  // zero-pad: wave-uniform skip
      const float* col = xb + (ci << 16) + (wc << 8);
      const int h0 = hbase + lane - P;
      float v0 = ((unsigned)h0 < 256u) ? col[h0] : 0.0f;
      float v1 = 0.0f;
      if (P > 0) {
        const int h1 = hbase + 64 - P + lane;
        v1 = (lane < 2 * P && (unsigned)h1 < 256u) ? col[h1] : 0.0f;
      }
#pragma unroll
      for (int kh = 0; kh < KS; kh++) {
        float tv;
        if (P == 0) {
          tv = v0;
        } else {
          const int s = lane + kh;  // tap source index in [0, 63+2P]
          float t0 = __shfl(v0, s & 63, 64);
          float t1 = __shfl(v1, (s - 64) & 63, 64);
          tv = (s < 64) ? t0 : t1;
        }
        const hv2 tp = pkrtz(tv, tv);
        const uint32_t* wp = wrh + ((ci * KS + kh) * KS + kw) * 8;
#pragma unroll
        for (int cp = 0; cp < 8; cp++)
          acc[cp] = pk_fma_n(i2h((int)wp[cp]), tp, acc[cp]);
      }
    }
  }
  float* o = cT + ((b * 16) << 16) + (w << 8) + hbase + lane;
#pragma unroll
  for (int cp = 0; cp < 8; cp++) {
    o[(2 * cp) << 16] = (float)acc[cp].x;
    o[(2 * cp + 1) << 16] = (float)acc[cp].y;
  }
}

// ---------------- packed-fp16 bitonic sort of 256 values: 64 lanes x 4 regs ----------------
__device__ __forceinline__ void ce_pair_h(hv2& a, hv2& b, bool up) {
  hv2 lo = pkmin(a, b);
  hv2 hi = pkmax(a, b);
  a = sel32(up, lo, hi);
  b = sel32(up, hi, lo);
}

template <int SIZE, int DIST>
__device__ __forceinline__ void stage_x_h(hv2 v[4], int i0) {
  const bool keepmin = (((i0 & DIST) == 0) == ((i0 & SIZE) == 0));
#pragma unroll
  for (int r = 0; r < 4; r++) {
    hv2 pv = i2h(lane_xor_i<(DIST >> 2)>(h2i(v[r])));
    v[r] = sel32(keepmin, pkmin(v[r], pv), pkmax(v[r], pv));
  }
}

template <int SIZE>
__device__ __forceinline__ void stage_d21_h(hv2 v[4], int i0) {
  bool up = ((i0 & SIZE) == 0);
  ce_pair_h(v[0], v[2], up); ce_pair_h(v[1], v[3], up);
  ce_pair_h(v[0], v[1], up); ce_pair_h(v[2], v[3], up);
}

__device__ __forceinline__ void sort256h(hv2 v[4], int lane) {
  int i0 = lane << 2;
  ce_pair_h(v[0], v[1], true); ce_pair_h(v[2], v[3], false);   // size 2
  stage_d21_h<4>(v, i0);                                       // size 4
  stage_x_h<8, 4>(v, i0); stage_d21_h<8>(v, i0);
  stage_x_h<16, 8>(v, i0); stage_x_h<16, 4>(v, i0); stage_d21_h<16>(v, i0);
  stage_x_h<32, 16>(v, i0); stage_x_h<32, 8>(v, i0); stage_x_h<32, 4>(v, i0); stage_d21_h<32>(v, i0);
  stage_x_h<64, 32>(v, i0); stage_x_h<64, 16>(v, i0); stage_x_h<64, 8>(v, i0); stage_x_h<64, 4>(v, i0); stage_d21_h<64>(v, i0);
  stage_x_h<128, 64>(v, i0); stage_x_h<128, 32>(v, i0); stage_x_h<128, 16>(v, i0); stage_x_h<128, 8>(v, i0); stage_x_h<128, 4>(v, i0); stage_d21_h<128>(v, i0);
  stage_x_h<256, 128>(v, i0); stage_x_h<256, 64>(v, i0); stage_x_h<256, 32>(v, i0); stage_x_h<256, 16>(v, i0); stage_x_h<256, 8>(v, i0); stage_x_h<256, 4>(v, i0); stage_d21_h<256>(v, i0);
}

// ---------------- fused diff/k3/mul/sort/silu/k4 + branch max/sum accum ----------------
template <int DIL>
__global__ __launch_bounds__(256) void k_branch(const float* __restrict__ cT,
                                                const float* __restrict__ ws,
                                                float* __restrict__ maxb,
                                                float* __restrict__ sumb,
                                                int initFlag) {
  const int tid = threadIdx.x;
  const int lane = tid & 63;
  // wave-uniform task id via readfirstlane -> scalar addressing + s_load weights
  const int wid = __builtin_amdgcn_readfirstlane(tid >> 6);
  const int wv = (blockIdx.x << 2) + wid;
  const int w = wv & 255;
  const int g = (wv >> 8) & 15;
  const int b = wv >> 12;
  const float* base = cT + ((b * 16 + g) << 16);

  float vals[3][3][4];
#pragma unroll
  for (int wi = 0; wi < 3; ++wi) {
    const int wc = w + (wi - 1) * DIL;
    const bool wok = ((unsigned)wc < 256u);
    const float* col = base + (wok ? wc : 0) * 256;
#pragma unroll
    for (int si = 0; si < 3; ++si) {
#pragma unroll
      for (int r = 0; r < 4; ++r) {
        const int h = lane + (r << 6) + (si - 1) * DIL;
        const bool ok = wok && ((unsigned)h < 256u);
        vals[wi][si][r] = ok ? col[h] : 0.0f;
      }
    }
  }
  // directional differences -> u/v sum-difference pairs (fp32), pack to fp16x2
  // u_j = dd_j + dd_{j+4}, v_j = dd_j - dd_{j+4}; o1 = s+d, o2 = s-d with
  // s = sum k3u_j u_j, d = sum k3v_j v_j  (halves the mixing FMA count)
  hv2 uh[4][4], vh[4][4];
#pragma unroll
  for (int r = 0; r < 4; ++r) {
    const float c0 = vals[1][1][r];
    float d0 = c0 - vals[0][0][r];  // (h-d, w-d)
    float d1 = c0 - vals[1][0][r];  // (h-d, w)
    float d2 = c0 - vals[2][0][r];  // (h-d, w+d)
    float d3 = c0 - vals[0][1][r];  // (h,   w-d)
    float d4 = c0 - vals[2][2][r];  // (h+d, w+d)
    float d5 = c0 - vals[1][2][r];  // (h+d, w)
    float d6 = c0 - vals[0][2][r];  // (h+d, w-d)
    float d7 = c0 - vals[2][1][r];  // (h,   w+d)
    uh[0][r] = pkrtz(d0 + d4, d0 + d4);
    uh[1][r] = pkrtz(d1 + d5, d1 + d5);
    uh[2][r] = pkrtz(d2 + d6, d2 + d6);
    uh[3][r] = pkrtz(d3 + d7, d3 + d7);
    vh[0][r] = pkrtz(d0 - d4, d0 - d4);
    vh[1][r] = pkrtz(d1 - d5, d1 - d5);
    vh[2][r] = pkrtz(d2 - d6, d2 - d6);
    vh[3][r] = pkrtz(d3 - d7, d3 - d7);
  }
  float out[4] = {0.f, 0.f, 0.f, 0.f};
  const uint32_t* k3u = (const uint32_t*)(ws + P_K3U) + g * 32;
  const uint32_t* k3v = (const uint32_t*)(ws + P_K3V) + g * 32;
  const float* k4p = ws + P_K4 + g * 16;
#pragma unroll 1
  for (int p = 0; p < 8; ++p) {
    hv2 t[4];
    hv2 wu[4], wvv[4];
#pragma unroll
    for (int j = 0; j < 4; ++j) {
      wu[j]  = i2h((int)k3u[p * 4 + j]);
      wvv[j] = i2h((int)k3v[p * 4 + j]);
    }
#pragma unroll
    for (int r = 0; r < 4; ++r) {
      hv2 s = pkmul(wu[0], uh[0][r]);
      s = pkfma(wu[1], uh[1][r], s);
      s = pkfma(wu[2], uh[2][r], s);
      s = pkfma(wu[3], uh[3][r], s);
      hv2 d = pkmul(wvv[0], vh[0][r]);
      d = pkfma(wvv[1], vh[1][r], d);
      d = pkfma(wvv[2], vh[2][r], d);
      d = pkfma(wvv[3], vh[3][r], d);
      t[r] = pkmul(s + d, s - d);  // o1*o2 exactly
    }
    sort256h(t, lane);
    const float k4a = k4p[2 * p], k4b = k4p[2 * p + 1];
#pragma unroll
    for (int r = 0; r < 4; ++r) {
      const float va = (float)t[r].x;
      const float vb = (float)t[r].y;
      out[r] = fmaf(k4a, va * sigmoid_fast(va), out[r]);
      out[r] = fmaf(k4b, vb * sigmoid_fast(vb), out[r]);
    }
  }
  const int obase = (((b * 16 + g) << 8) + w) * 256 + (lane << 2);
  float4 o4 = make_float4(out[0], out[1], out[2], out[3]);
  float4* mp = (float4*)(maxb + obase);
  float4* sp = (float4*)(sumb + obase);
  if (initFlag) {
    *mp = o4;
    *sp = o4;
  } else {
    float4 m = *mp;
    m.x = fmaxf(m.x, o4.x); m.y = fmaxf(m.y, o4.y);
    m.z = fmaxf(m.z, o4.z); m.w = fmaxf(m.w, o4.w);
    *mp = m;
    float4 s = *sp;
    s.x += o4.x; s.y += o4.y; s.z += o4.z; s.w += o4.w;
    *sp = s;
  }
}

// ---------------- combine + 3x3 conv + BN + SiLU + 1x1 + sigmoid + GATE (fused tail) ----------------
__global__ __launch_bounds__(256) void k_tail(const float* __restrict__ maxb,
                                              const float* __restrict__ sumb,
                                              const float* __restrict__ ws,
                                              const float* __restrict__ cen,
                                              const float* __restrict__ mas,
                                              const float* __restrict__ w_out,
                                              const float* __restrict__ b_out,
                                              float* __restrict__ out) {
  __shared__ float lds[16 * 18 * 18];
  __shared__ float ldsf[256];
  int tid = threadIdx.x;
  int b = blockIdx.z;
  int wbase = blockIdx.x * 16, hbase = blockIdx.y * 16;
  const float* mb = maxb + (b * 16) * HW;  // [g][w][h]
  const float* sb = sumb + (b * 16) * HW;
  for (int i = tid; i < 16 * 18 * 18; i += 256) {
    int g = i / 324; int r = i % 324; int xx = r / 18, yy = r % 18;
    int wq = wbase + xx - 1, hq = hbase + yy - 1;
    float v = 0.0f;
    if (wq >= 0 && wq < 256 && hq >= 0 && hq < 256) {
      int idx = g * HW + wq * 256 + hq;
      v = mb[idx] + 0.25f * sb[idx];
    }
    lds[i] = v;
  }
  __syncthreads();
  int xw = tid >> 4, yh = tid & 15;  // pixel (w = wbase+xw, h = hbase+yh)
  float acc[16] = {0.f, 0.f, 0.f, 0.f, 0.f, 0.f, 0.f, 0.f,
                   0.f, 0.f, 0.f, 0.f, 0.f, 0.f, 0.f, 0.f};
  for (int g = 0; g < 16; g++) {
#pragma unroll
    for (int kw = 0; kw < 3; kw++) {
#pragma unroll
      for (int kh = 0; kh < 3; kh++) {
        float v = lds[g * 324 + (xw + kw) * 18 + (yh + kh)];
        const float* wp = ws + P_WRB + ((g * 3 + kw) * 3 + kh) * 16;
#pragma unroll
        for (int co = 0; co < 16; co++) acc[co] = fmaf(wp[co], v, acc[co]);
      }
    }
  }
  float mo = b_out[0];
#pragma unroll
  for (int co = 0; co < 16; co++) {
    float z = acc[co] * ws[P_BNS + co] + ws[P_BNB + co];
    float sl = z * sigmoid_fast(z);
    mo = fmaf(w_out[co], sl, mo);
  }
  float mk = sigmoid_fast(mo);
  ldsf[yh * 16 + xw] = mk;
  __syncthreads();
  // compute gate factor f per pixel under coalesced (yy,xx) mapping
  {
    int yy = tid >> 4, xx = tid & 15;
    float mkv = ldsf[yy * 16 + xx];
    float m = sigmoid_fast(mas[b * HW + (hbase + yy) * 256 + wbase + xx]);
    float s0 = ws[P_S1], s1 = ws[P_S1 + 1], s2 = ws[P_S1 + 2], s3 = ws[P_S1 + 3];
    float f = mkv * m * s0 + m * s1 + s2 * mkv + s3;
    ldsf[yy * 16 + xx] = f;  // each thread overwrites the slot it just read
  }
  __syncthreads();
  // gate all 64 cen channels, float4 over w
  const float* cb = cen + b * 64 * HW;
  float* ob = out + b * 64 * HW;
#pragma unroll 4
  for (int it = 0; it < 16; ++it) {
    int flat = it * 256 + tid;
    int ci = flat >> 6;
    int rr = flat & 63;
    int yy = rr >> 2, wq = rr & 3;
    const float* fr = &ldsf[yy * 16 + wq * 4];
    float4 f4 = make_float4(fr[0], fr[1], fr[2], fr[3]);
    int addr = ci * HW + (hbase + yy) * 256 + wbase + wq * 4;
    const float4 c4 = *(const float4*)(cb + addr);
    float4 o4;
    o4.x = c4.x * f4.x; o4.y = c4.y * f4.y; o4.z = c4.z * f4.z; o4.w = c4.w * f4.w;
    *(float4*)(ob + addr) = o4;
  }
}

extern "C" void kernel_launch(void* const* d_in, const int* in_sizes, int n_in,
                              void* d_out, int out_size, void* d_ws, size_t ws_size,
                              hipStream_t stream) {
  (void)in_sizes; (void)n_in; (void)out_size; (void)ws_size;
  const float* cen = (const float*)d_in[0];
  const float* mas = (const float*)d_in[1];
  const float* w_in = (const float*)d_in[2];
  const float* b_in = (const float*)d_in[3];
  const float* w_c0 = (const float*)d_in[4];
  const float* b_c0 = (const float*)d_in[5];
  const float* w_c1 = (const float*)d_in[6];
  const float* b_c1 = (const float*)d_in[7];
  const float* w_c2 = (const float*)d_in[8];
  const float* b_c2 = (const float*)d_in[9];
  const float* w_c3 = (const float*)d_in[10];
  const float* b_c3 = (const float*)d_in[11];
  const float* scales1 = (const float*)d_in[12];
  const float* scales2 = (const float*)d_in[13];
  const float* scales3 = (const float*)d_in[14];
  const float* w_base = (const float*)d_in[15];
  const float* bn_gamma = (const float*)d_in[16];
  const float* bn_beta = (const float*)d_in[17];
  const float* bn_mean = (const float*)d_in[18];
  const float* bn_var = (const float*)d_in[19];
  const float* w_out = (const float*)d_in[20];
  const float* b_out = (const float*)d_in[21];
  float* ws = (float*)d_ws;
  float* out = (float*)d_out;

  float* xT = ws + OFF_X;
  float* cT = ws + OFF_CT;
  float* maxb = ws + OFF_MAX;
  float* sumb = ws + OFF_SUM;

  k_prep<<<1, 256, 0, stream>>>(w_in, w_c0, w_c1, w_c2, w_c3, w_base, scales1, scales2,
                                scales3, bn_gamma, bn_beta, bn_mean, bn_var, ws);
  k_in<<<dim3(16, 16, 4), 256, 0, stream>>>(cen, b_in, ws, xT);

  k_conv<1><<<1024, 256, 0, stream>>>(xT, b_c0, (const uint32_t*)(ws + P_WR0), cT);
  k_branch<1><<<4096, 256, 0, stream>>>(cT, ws, maxb, sumb, 1);
  k_conv<3><<<1024, 256, 0, stream>>>(xT, b_c1, (const uint32_t*)(ws + P_WR1), cT);
  k_branch<3><<<4096, 256, 0, stream>>>(cT, ws, maxb, sumb, 0);
  k_conv<5><<<1024, 256, 0, stream>>>(xT, b_c2, (const uint32_t*)(ws + P_WR2), cT);
  k_branch<5><<<4096, 256, 0, stream>>>(cT, ws, maxb, sumb, 0);
  k_conv<7><<<1024, 256, 0, stream>>>(xT, b_c3, (const uint32_t*)(ws + P_WR3), cT);
  k_branch<7><<<4096, 256, 0, stream>>>(cT, ws, maxb, sumb, 0);

  k_tail<<<dim3(16, 16, 4), 256, 0, stream>>>(maxb, sumb, ws, cen, mas, w_out, b_out, out);
}

// Round 13
// 864.906 us; speedup vs baseline: 1.0860x; 1.0231x over previous
//
#include <hip/hip_runtime.h>

#define HW 65536

// ---- ws layout (float offsets) ----
constexpr int OFF_X    = 0;          // xT: 4b*16ci*256w*256h (transposed)
constexpr int OFF_CT   = 4194304;    // c transposed [b][g][w][h]
constexpr int OFF_MAX  = 8388608;
constexpr int OFF_SUM  = 12582912;
constexpr int P_K3  = 17039360;          // 256*8 softmax(scales2)
constexpr int P_K3S = P_K3  + 2048;      // (unused now)
constexpr int P_K4  = P_K3S + 2048;      // 16*16 softmax(scales3)
constexpr int P_S1  = P_K4  + 256;       // softmax(scales1), 4
constexpr int P_BNS = P_S1  + 4;         // 16
constexpr int P_BNB = P_BNS + 16;        // 16
constexpr int P_WRI = P_BNB + 16;        // w_in  re-laid [ci][co] 1024
// conv weights packed fp16 co-pairs (uint32)
constexpr int P_WR0 = P_WRI + 1024;      // 128 u32  (1x1)
constexpr int P_WR1 = P_WR0 + 256;       // 1152 u32 (3x3)
constexpr int P_WR2 = P_WR1 + 2304;      // 3200 u32 (5x5)
constexpr int P_WR3 = P_WR2 + 6400;      // 6272 u32 (7x7)
constexpr int P_WRB = P_WR3 + 12544;     // 2304 fp32 (tail 3x3)
constexpr int P_K3U = P_WRB + 2304;      // packed fp16 (k3[j]+k3[j+4])/2: 16g*8p*4j = 512 u32
constexpr int P_K3V = P_K3U + 512;       // packed fp16 (k3[j]-k3[j+4])/2: 512 u32

// clang-native packed fp16
typedef _Float16 hv2 __attribute__((ext_vector_type(2)));

__device__ __forceinline__ int h2i(hv2 v) { return __builtin_bit_cast(int, v); }
__device__ __forceinline__ hv2 i2h(int v) { return __builtin_bit_cast(hv2, v); }

// __builtin_amdgcn_cvt_pkrtz returns __fp16 ext_vector(2); bit-cast to hv2
__device__ __forceinline__ hv2 pkrtz(float a, float b) {
  return __builtin_bit_cast(hv2, __builtin_amdgcn_cvt_pkrtz(a, b));
}

// native packed fma (compiler folds uniform operands)
__device__ __forceinline__ hv2 pk_fma_n(hv2 a, hv2 b, hv2 c) {
#if __has_builtin(__builtin_elementwise_fma)
  return __builtin_elementwise_fma(a, b, c);
#else
  return a * b + c;
#endif
}

// guaranteed-packed fp16 ops (one VOP3P inst each)
__device__ __forceinline__ hv2 pkmin(hv2 a, hv2 b) {
  hv2 d; asm("v_pk_min_f16 %0, %1, %2" : "=v"(d) : "v"(a), "v"(b)); return d;
}
__device__ __forceinline__ hv2 pkmax(hv2 a, hv2 b) {
  hv2 d; asm("v_pk_max_f16 %0, %1, %2" : "=v"(d) : "v"(a), "v"(b)); return d;
}
__device__ __forceinline__ hv2 pkmul(hv2 a, hv2 b) {
  hv2 d; asm("v_pk_mul_f16 %0, %1, %2" : "=v"(d) : "v"(a), "v"(b)); return d;
}
__device__ __forceinline__ hv2 pkfma(hv2 a, hv2 b, hv2 c) {
  hv2 d; asm("v_pk_fma_f16 %0, %1, %2, %3" : "=v"(d) : "v"(a), "v"(b), "v"(c)); return d;
}

// 32-bit select -> single v_cndmask_b32
__device__ __forceinline__ hv2 sel32(bool c, hv2 a, hv2 b) {
  return i2h(c ? h2i(a) : h2i(b));
}

// cross-lane xor: ds_swizzle (DS pipe, free when VALU-bound) for <32, shfl for 32
template <int LMASK>
__device__ __forceinline__ int lane_xor_i(int x) {
  if constexpr (LMASK < 32) {
    return __builtin_amdgcn_ds_swizzle(x, (LMASK << 10) | 0x1F);
  } else {
    return __shfl_xor(x, LMASK, 64);
  }
}

__device__ __forceinline__ float sigmoid_fast(float x) {
  return __fdividef(1.0f, 1.0f + __expf(-x));
}

// ---------------- prep ----------------
__global__ void k_prep(const float* __restrict__ w_in, const float* __restrict__ w_c0,
                       const float* __restrict__ w_c1, const float* __restrict__ w_c2,
                       const float* __restrict__ w_c3, const float* __restrict__ w_base,
                       const float* __restrict__ scales1, const float* __restrict__ scales2,
                       const float* __restrict__ scales3, const float* __restrict__ bn_gamma,
                       const float* __restrict__ bn_beta, const float* __restrict__ bn_mean,
                       const float* __restrict__ bn_var, float* __restrict__ ws) {
  int tid = threadIdx.x;  // 256
  {
    const float* srow = scales2 + tid * 8;
    float v[8]; float mx = -1e30f;
    for (int j = 0; j < 8; j++) { v[j] = srow[j]; mx = fmaxf(mx, v[j]); }
    float s = 0.f;
    for (int j = 0; j < 8; j++) { v[j] = __expf(v[j] - mx); s += v[j]; }
    float inv = 1.0f / s;
    for (int j = 0; j < 8; j++) ws[P_K3 + tid * 8 + j] = v[j] * inv;
  }
  if (tid < 16) {
    const float* srow = scales3 + tid * 16;
    float v[16]; float mx = -1e30f;
    for (int e = 0; e < 16; e++) { v[e] = srow[e]; mx = fmaxf(mx, v[e]); }
    float s = 0.f;
    for (int e = 0; e < 16; e++) { v[e] = __expf(v[e] - mx); s += v[e]; }
    float inv = 1.0f / s;
    for (int e = 0; e < 16; e++) ws[P_K4 + tid * 16 + e] = v[e] * inv;
  }
  if (tid == 0) {
    float v[4]; float mx = -1e30f;
    for (int i = 0; i < 4; i++) { v[i] = scales1[i]; mx = fmaxf(mx, v[i]); }
    float s = 0.f;
    for (int i = 0; i < 4; i++) { v[i] = __expf(v[i] - mx); s += v[i]; }
    for (int i = 0; i < 4; i++) ws[P_S1 + i] = v[i] / s;
  }
  if (tid < 16) {
    float rs = rsqrtf(bn_var[tid] + 1e-5f);
    float sc = bn_gamma[tid] * rs;
    ws[P_BNS + tid] = sc;
    ws[P_BNB + tid] = bn_beta[tid] - bn_mean[tid] * sc;
  }
  for (int i = tid; i < 1024; i += 256) { int ci = i >> 4, co = i & 15; ws[P_WRI + i] = w_in[co * 64 + ci]; }
  // packed fp16 co-pair conv weights
  {
    uint32_t* w0 = (uint32_t*)(ws + P_WR0);
    for (int i = tid; i < 128; i += 256) {
      int cp = i & 7, ci = i >> 3;
      hv2 wv;
      wv.x = (_Float16)w_c0[(2 * cp) * 16 + ci];
      wv.y = (_Float16)w_c0[(2 * cp + 1) * 16 + ci];
      w0[ci * 8 + cp] = __builtin_bit_cast(uint32_t, wv);
    }
    uint32_t* w1 = (uint32_t*)(ws + P_WR1);
    for (int i = tid; i < 1152; i += 256) {
      int cp = i & 7; int r = i >> 3; int kw = r % 3; r /= 3; int kh = r % 3; int ci = r / 3;
      hv2 wv;
      wv.x = (_Float16)w_c1[((2 * cp) * 16 + ci) * 9 + kh * 3 + kw];
      wv.y = (_Float16)w_c1[((2 * cp + 1) * 16 + ci) * 9 + kh * 3 + kw];
      w1[((ci * 3 + kh) * 3 + kw) * 8 + cp] = __builtin_bit_cast(uint32_t, wv);
    }
    uint32_t* w2 = (uint32_t*)(ws + P_WR2);
    for (int i = tid; i < 3200; i += 256) {
      int cp = i & 7; int r = i >> 3; int kw = r % 5; r /= 5; int kh = r % 5; int ci = r / 5;
      hv2 wv;
      wv.x = (_Float16)w_c2[((2 * cp) * 16 + ci) * 25 + kh * 5 + kw];
      wv.y = (_Float16)w_c2[((2 * cp + 1) * 16 + ci) * 25 + kh * 5 + kw];
      w2[((ci * 5 + kh) * 5 + kw) * 8 + cp] = __builtin_bit_cast(uint32_t, wv);
    }
    uint32_t* w3 = (uint32_t*)(ws + P_WR3);
    for (int i = tid; i < 6272; i += 256) {
      int cp = i & 7; int r = i >> 3; int kw = r % 7; r /= 7; int kh = r % 7; int ci = r / 7;
      hv2 wv;
      wv.x = (_Float16)w_c3[((2 * cp) * 16 + ci) * 49 + kh * 7 + kw];
      wv.y = (_Float16)w_c3[((2 * cp + 1) * 16 + ci) * 49 + kh * 7 + kw];
      w3[((ci * 7 + kh) * 7 + kw) * 8 + cp] = __builtin_bit_cast(uint32_t, wv);
    }
  }
  // wbr[((g*3+kw)*3+kh)*16+co] = w_base[co][g][kh][kw]  (fp32, tail conv)
  for (int i = tid; i < 2304; i += 256) {
    int co = i & 15; int r = i >> 4; int kh = r % 3; r /= 3; int kw = r % 3; int g = r / 3;
    ws[P_WRB + i] = w_base[((co * 16 + g) * 3 + kh) * 3 + kw];
  }
  __syncthreads();
  // factored k3 weights: k3u = (k3[j]+k3[j+4])/2, k3v = (k3[j]-k3[j+4])/2, j=0..3
  uint32_t* k3u = (uint32_t*)(ws + P_K3U);
  uint32_t* k3v = (uint32_t*)(ws + P_K3V);
  for (int i = tid; i < 512; i += 256) {
    int g = i >> 5, p = (i >> 2) & 7, j = i & 3;
    const float* r0 = ws + P_K3 + g * 128 + (2 * p) * 8;
    const float* r1 = ws + P_K3 + g * 128 + (2 * p + 1) * 8;
    hv2 wu, wv;
    wu.x = (_Float16)((r0[j] + r0[j + 4]) * 0.5f);
    wu.y = (_Float16)((r1[j] + r1[j + 4]) * 0.5f);
    wv.x = (_Float16)((r0[j] - r0[j + 4]) * 0.5f);
    wv.y = (_Float16)((r1[j] - r1[j + 4]) * 0.5f);
    k3u[i] = __builtin_bit_cast(uint32_t, wu);
    k3v[i] = __builtin_bit_cast(uint32_t, wv);
  }
}

// ---------------- 1x1 conv 64->16, writes TRANSPOSED xT[b][ci][w][h] ----------------
__global__ __launch_bounds__(256) void k_in(const float* __restrict__ cen,
                                            const float* __restrict__ b_in,
                                            const float* __restrict__ ws,
                                            float* __restrict__ xT) {
  __shared__ float ldst[16 * 16 * 17];  // [co][tx(w)][ty(h)] padded
  int tid = threadIdx.x;
  int b = blockIdx.z;
  int hbase = blockIdx.y * 16, wbase = blockIdx.x * 16;
  int ty = tid >> 4, tx = tid & 15;  // h, w within tile
  const float* wri = ws + P_WRI;
  float acc[16];
#pragma unroll
  for (int co = 0; co < 16; co++) acc[co] = b_in[co];
  const float* cp = cen + b * 64 * HW + (hbase + ty) * 256 + wbase + tx;
#pragma unroll 4
  for (int ci = 0; ci < 64; ci++) {
    float v = cp[ci * HW];
#pragma unroll
    for (int co = 0; co < 16; co++) acc[co] = fmaf(wri[ci * 16 + co], v, acc[co]);
  }
#pragma unroll
  for (int co = 0; co < 16; co++) ldst[(co * 16 + tx) * 17 + ty] = acc[co];
  __syncthreads();
  int wy = tid >> 4, hx = tid & 15;  // w, h for transposed write
#pragma unroll
  for (int ci = 0; ci < 16; ci++) {
    xT[((b * 16 + ci) << 16) + (wbase + wy) * 256 + hbase + hx] =
        ldst[(ci * 16 + wy) * 17 + hx];
  }
}

// ---------------- branch conv: direct per-kh offset loads (no shuffles, no DS) ----------------
// SAFE=true: interior h-segment, loads unconditionally in-bounds
template <int KS, bool SAFE>
__device__ __forceinline__ void conv_body(const float* __restrict__ xb,
                                          const uint32_t* __restrict__ wrh,
                                          int w, int hbase, int lane, hv2 acc[8]) {
  constexpr int P = KS / 2;
#pragma unroll 2
  for (int ci = 0; ci < 16; ci++) {
#pragma unroll
    for (int kw = 0; kw < KS; kw++) {
      const int wc = w + kw - P;
      if (KS > 1 && (unsigned)wc >= 256u) continue;  // zero-pad: wave-uniform skip
      const float* col = xb + (ci << 16) + (wc << 8);
      const int hb = hbase + lane - P;
#pragma unroll
      for (int kh = 0; kh < KS; kh++) {
        float tv;
        if constexpr (SAFE) {
          tv = col[hb + kh];
        } else {
          const int h = hb + kh;
          tv = ((unsigned)h < 256u) ? col[h] : 0.0f;
        }
        const hv2 tp = pkrtz(tv, tv);
        const uint32_t* wp = wrh + ((ci * KS + kh) * KS + kw) * 8;
#pragma unroll
        for (int cp = 0; cp < 8; cp++)
          acc[cp] = pk_fma_n(i2h((int)wp[cp]), tp, acc[cp]);
      }
    }
  }
}

template <int KS>
__global__ __launch_bounds__(256) void k_conv(const float* __restrict__ xT,
                                              const float* __restrict__ bias,
                                              const uint32_t* __restrict__ wrh,
                                              float* __restrict__ cT) {
  const int tid = threadIdx.x;
  const int lane = tid & 63;
  const int wv = (blockIdx.x << 2) + (tid >> 6);  // 4096 waves: b(4) x w(256) x hseg(4)
  const int hseg = wv & 3;
  const int w = (wv >> 2) & 255;
  const int b = wv >> 10;
  const int hbase = hseg << 6;
  const float* xb = xT + ((b * 16) << 16);

  hv2 acc[8];
#pragma unroll
  for (int cp = 0; cp < 8; cp++) {
    hv2 bv;
    bv.x = (_Float16)bias[2 * cp];
    bv.y = (_Float16)bias[2 * cp + 1];
    acc[cp] = bv;
  }

  if (KS == 1 || (hseg != 0 && hseg != 3)) {
    conv_body<KS, true>(xb, wrh, w, hbase, lane, acc);
  } else {
    conv_body<KS, false>(xb, wrh, w, hbase, lane, acc);
  }

  float* o = cT + ((b * 16) << 16) + (w << 8) + hbase + lane;
#pragma unroll
  for (int cp = 0; cp < 8; cp++) {
    o[(2 * cp) << 16] = (float)acc[cp].x;
    o[(2 * cp + 1) << 16] = (float)acc[cp].y;
  }
}

// ---------------- packed-fp16 bitonic sort of 256 values: 64 lanes x 4 regs ----------------
__device__ __forceinline__ void ce_pair_h(hv2& a, hv2& b, bool up) {
  hv2 lo = pkmin(a, b);
  hv2 hi = pkmax(a, b);
  a = sel32(up, lo, hi);
  b = sel32(up, hi, lo);
}

template <int SIZE, int DIST>
__device__ __forceinline__ void stage_x_h(hv2 v[4], int i0) {
  const bool keepmin = (((i0 & DIST) == 0) == ((i0 & SIZE) == 0));
#pragma unroll
  for (int r = 0; r < 4; r++) {
    hv2 pv = i2h(lane_xor_i<(DIST >> 2)>(h2i(v[r])));
    v[r] = sel32(keepmin, pkmin(v[r], pv), pkmax(v[r], pv));
  }
}

template <int SIZE>
__device__ __forceinline__ void stage_d21_h(hv2 v[4], int i0) {
  bool up = ((i0 & SIZE) == 0);
  ce_pair_h(v[0], v[2], up); ce_pair_h(v[1], v[3], up);
  ce_pair_h(v[0], v[1], up); ce_pair_h(v[2], v[3], up);
}

__device__ __forceinline__ void sort256h(hv2 v[4], int lane) {
  int i0 = lane << 2;
  ce_pair_h(v[0], v[1], true); ce_pair_h(v[2], v[3], false);   // size 2
  stage_d21_h<4>(v, i0);                                       // size 4
  stage_x_h<8, 4>(v, i0); stage_d21_h<8>(v, i0);
  stage_x_h<16, 8>(v, i0); stage_x_h<16, 4>(v, i0); stage_d21_h<16>(v, i0);
  stage_x_h<32, 16>(v, i0); stage_x_h<32, 8>(v, i0); stage_x_h<32, 4>(v, i0); stage_d21_h<32>(v, i0);
  stage_x_h<64, 32>(v, i0); stage_x_h<64, 16>(v, i0); stage_x_h<64, 8>(v, i0); stage_x_h<64, 4>(v, i0); stage_d21_h<64>(v, i0);
  stage_x_h<128, 64>(v, i0); stage_x_h<128, 32>(v, i0); stage_x_h<128, 16>(v, i0); stage_x_h<128, 8>(v, i0); stage_x_h<128, 4>(v, i0); stage_d21_h<128>(v, i0);
  stage_x_h<256, 128>(v, i0); stage_x_h<256, 64>(v, i0); stage_x_h<256, 32>(v, i0); stage_x_h<256, 16>(v, i0); stage_x_h<256, 8>(v, i0); stage_x_h<256, 4>(v, i0); stage_d21_h<256>(v, i0);
}

// ---------------- fused diff/k3/mul/sort/silu/k4 + branch max/sum accum ----------------
template <int DIL>
__global__ __launch_bounds__(256) void k_branch(const float* __restrict__ cT,
                                                const float* __restrict__ ws,
                                                float* __restrict__ maxb,
                                                float* __restrict__ sumb,
                                                int initFlag) {
  const int tid = threadIdx.x;
  const int lane = tid & 63;
  // wave-uniform task id via readfirstlane -> scalar addressing + s_load weights
  const int wid = __builtin_amdgcn_readfirstlane(tid >> 6);
  const int wv = (blockIdx.x << 2) + wid;
  const int w = wv & 255;
  const int g = (wv >> 8) & 15;
  const int b = wv >> 12;
  const float* base = cT + ((b * 16 + g) << 16);

  float vals[3][3][4];
#pragma unroll
  for (int wi = 0; wi < 3; ++wi) {
    const int wc = w + (wi - 1) * DIL;
    const bool wok = ((unsigned)wc < 256u);
    const float* col = base + (wok ? wc : 0) * 256;
#pragma unroll
    for (int si = 0; si < 3; ++si) {
#pragma unroll
      for (int r = 0; r < 4; ++r) {
        const int h = lane + (r << 6) + (si - 1) * DIL;
        const bool ok = wok && ((unsigned)h < 256u);
        vals[wi][si][r] = ok ? col[h] : 0.0f;
      }
    }
  }
  // directional differences -> u/v sum-difference pairs (fp32), pack to fp16x2
  hv2 uh[4][4], vh[4][4];
#pragma unroll
  for (int r = 0; r < 4; ++r) {
    const float c0 = vals[1][1][r];
    float d0 = c0 - vals[0][0][r];  // (h-d, w-d)
    float d1 = c0 - vals[1][0][r];  // (h-d, w)
    float d2 = c0 - vals[2][0][r];  // (h-d, w+d)
    float d3 = c0 - vals[0][1][r];  // (h,   w-d)
    float d4 = c0 - vals[2][2][r];  // (h+d, w+d)
    float d5 = c0 - vals[1][2][r];  // (h+d, w)
    float d6 = c0 - vals[0][2][r];  // (h+d, w-d)
    float d7 = c0 - vals[2][1][r];  // (h,   w+d)
    uh[0][r] = pkrtz(d0 + d4, d0 + d4);
    uh[1][r] = pkrtz(d1 + d5, d1 + d5);
    uh[2][r] = pkrtz(d2 + d6, d2 + d6);
    uh[3][r] = pkrtz(d3 + d7, d3 + d7);
    vh[0][r] = pkrtz(d0 - d4, d0 - d4);
    vh[1][r] = pkrtz(d1 - d5, d1 - d5);
    vh[2][r] = pkrtz(d2 - d6, d2 - d6);
    vh[3][r] = pkrtz(d3 - d7, d3 - d7);
  }
  float out[4] = {0.f, 0.f, 0.f, 0.f};
  const uint32_t* k3u = (const uint32_t*)(ws + P_K3U) + g * 32;
  const uint32_t* k3v = (const uint32_t*)(ws + P_K3V) + g * 32;
  const float* k4p = ws + P_K4 + g * 16;
#pragma unroll 1
  for (int p = 0; p < 8; ++p) {
    hv2 t[4];
    hv2 wu[4], wvv[4];
#pragma unroll
    for (int j = 0; j < 4; ++j) {
      wu[j]  = i2h((int)k3u[p * 4 + j]);
      wvv[j] = i2h((int)k3v[p * 4 + j]);
    }
#pragma unroll
    for (int r = 0; r < 4; ++r) {
      hv2 s = pkmul(wu[0], uh[0][r]);
      s = pkfma(wu[1], uh[1][r], s);
      s = pkfma(wu[2], uh[2][r], s);
      s = pkfma(wu[3], uh[3][r], s);
      hv2 d = pkmul(wvv[0], vh[0][r]);
      d = pkfma(wvv[1], vh[1][r], d);
      d = pkfma(wvv[2], vh[2][r], d);
      d = pkfma(wvv[3], vh[3][r], d);
      t[r] = pkmul(s + d, s - d);  // o1*o2 exactly
    }
    sort256h(t, lane);
    const float k4a = k4p[2 * p], k4b = k4p[2 * p + 1];
#pragma unroll
    for (int r = 0; r < 4; ++r) {
      const float va = (float)t[r].x;
      const float vb = (float)t[r].y;
      out[r] = fmaf(k4a, va * sigmoid_fast(va), out[r]);
      out[r] = fmaf(k4b, vb * sigmoid_fast(vb), out[r]);
    }
  }
  const int obase = (((b * 16 + g) << 8) + w) * 256 + (lane << 2);
  float4 o4 = make_float4(out[0], out[1], out[2], out[3]);
  float4* mp = (float4*)(maxb + obase);
  float4* sp = (float4*)(sumb + obase);
  if (initFlag) {
    *mp = o4;
    *sp = o4;
  } else {
    float4 m = *mp;
    m.x = fmaxf(m.x, o4.x); m.y = fmaxf(m.y, o4.y);
    m.z = fmaxf(m.z, o4.z); m.w = fmaxf(m.w, o4.w);
    *mp = m;
    float4 s = *sp;
    s.x += o4.x; s.y += o4.y; s.z += o4.z; s.w += o4.w;
    *sp = s;
  }
}

// ---------------- combine + 3x3 conv + BN + SiLU + 1x1 + sigmoid + GATE (fused tail) ----------------
__global__ __launch_bounds__(256) void k_tail(const float* __restrict__ maxb,
                                              const float* __restrict__ sumb,
                                              const float* __restrict__ ws,
                                              const float* __restrict__ cen,
                                              const float* __restrict__ mas,
                                              const float* __restrict__ w_out,
                                              const float* __restrict__ b_out,
                                              float* __restrict__ out) {
  __shared__ float lds[16 * 18 * 18];
  __shared__ float ldsf[256];
  int tid = threadIdx.x;
  int b = blockIdx.z;
  int wbase = blockIdx.x * 16, hbase = blockIdx.y * 16;
  const float* mb = maxb + (b * 16) * HW;  // [g][w][h]
  const float* sb = sumb + (b * 16) * HW;
  for (int i = tid; i < 16 * 18 * 18; i += 256) {
    int g = i / 324; int r = i % 324; int xx = r / 18, yy = r % 18;
    int wq = wbase + xx - 1, hq = hbase + yy - 1;
    float v = 0.0f;
    if (wq >= 0 && wq < 256 && hq >= 0 && hq < 256) {
      int idx = g * HW + wq * 256 + hq;
      v = mb[idx] + 0.25f * sb[idx];
    }
    lds[i] = v;
  }
  __syncthreads();
  int xw = tid >> 4, yh = tid & 15;  // pixel (w = wbase+xw, h = hbase+yh)
  float acc[16] = {0.f, 0.f, 0.f, 0.f, 0.f, 0.f, 0.f, 0.f,
                   0.f, 0.f, 0.f, 0.f, 0.f, 0.f, 0.f, 0.f};
  for (int g = 0; g < 16; g++) {
#pragma unroll
    for (int kw = 0; kw < 3; kw++) {
#pragma unroll
      for (int kh = 0; kh < 3; kh++) {
        float v = lds[g * 324 + (xw + kw) * 18 + (yh + kh)];
        const float* wp = ws + P_WRB + ((g * 3 + kw) * 3 + kh) * 16;
#pragma unroll
        for (int co = 0; co < 16; co++) acc[co] = fmaf(wp[co], v, acc[co]);
      }
    }
  }
  float mo = b_out[0];
#pragma unroll
  for (int co = 0; co < 16; co++) {
    float z = acc[co] * ws[P_BNS + co] + ws[P_BNB + co];
    float sl = z * sigmoid_fast(z);
    mo = fmaf(w_out[co], sl, mo);
  }
  float mk = sigmoid_fast(mo);
  ldsf[yh * 16 + xw] = mk;
  __syncthreads();
  // compute gate factor f per pixel under coalesced (yy,xx) mapping
  {
    int yy = tid >> 4, xx = tid & 15;
    float mkv = ldsf[yy * 16 + xx];
    float m = sigmoid_fast(mas[b * HW + (hbase + yy) * 256 + wbase + xx]);
    float s0 = ws[P_S1], s1 = ws[P_S1 + 1], s2 = ws[P_S1 + 2], s3 = ws[P_S1 + 3];
    float f = mkv * m * s0 + m * s1 + s2 * mkv + s3;
    ldsf[yy * 16 + xx] = f;  // each thread overwrites the slot it just read
  }
  __syncthreads();
  // gate all 64 cen channels, float4 over w
  const float* cb = cen + b * 64 * HW;
  float* ob = out + b * 64 * HW;
#pragma unroll 4
  for (int it = 0; it < 16; ++it) {
    int flat = it * 256 + tid;
    int ci = flat >> 6;
    int rr = flat & 63;
    int yy = rr >> 2, wq = rr & 3;
    const float* fr = &ldsf[yy * 16 + wq * 4];
    float4 f4 = make_float4(fr[0], fr[1], fr[2], fr[3]);
    int addr = ci * HW + (hbase + yy) * 256 + wbase + wq * 4;
    const float4 c4 = *(const float4*)(cb + addr);
    float4 o4;
    o4.x = c4.x * f4.x; o4.y = c4.y * f4.y; o4.z = c4.z * f4.z; o4.w = c4.w * f4.w;
    *(float4*)(ob + addr) = o4;
  }
}

extern "C" void kernel_launch(void* const* d_in, const int* in_sizes, int n_in,
                              void* d_out, int out_size, void* d_ws, size_t ws_size,
                              hipStream_t stream) {
  (void)in_sizes; (void)n_in; (void)out_size; (void)ws_size;
  const float* cen = (const float*)d_in[0];
  const float* mas = (const float*)d_in[1];
  const float* w_in = (const float*)d_in[2];
  const float* b_in = (const float*)d_in[3];
  const float* w_c0 = (const float*)d_in[4];
  const float* b_c0 = (const float*)d_in[5];
  const float* w_c1 = (const float*)d_in[6];
  const float* b_c1 = (const float*)d_in[7];
  const float* w_c2 = (const float*)d_in[8];
  const float* b_c2 = (const float*)d_in[9];
  const float* w_c3 = (const float*)d_in[10];
  const float* b_c3 = (const float*)d_in[11];
  const float* scales1 = (const float*)d_in[12];
  const float* scales2 = (const float*)d_in[13];
  const float* scales3 = (const float*)d_in[14];
  const float* w_base = (const float*)d_in[15];
  const float* bn_gamma = (const float*)d_in[16];
  const float* bn_beta = (const float*)d_in[17];
  const float* bn_mean = (const float*)d_in[18];
  const float* bn_var = (const float*)d_in[19];
  const float* w_out = (const float*)d_in[20];
  const float* b_out = (const float*)d_in[21];
  float* ws = (float*)d_ws;
  float* out = (float*)d_out;

  float* xT = ws + OFF_X;
  float* cT = ws + OFF_CT;
  float* maxb = ws + OFF_MAX;
  float* sumb = ws + OFF_SUM;

  k_prep<<<1, 256, 0, stream>>>(w_in, w_c0, w_c1, w_c2, w_c3, w_base, scales1, scales2,
                                scales3, bn_gamma, bn_beta, bn_mean, bn_var, ws);
  k_in<<<dim3(16, 16, 4), 256, 0, stream>>>(cen, b_in, ws, xT);

  k_conv<1><<<1024, 256, 0, stream>>>(xT, b_c0, (const uint32_t*)(ws + P_WR0), cT);
  k_branch<1><<<4096, 256, 0, stream>>>(cT, ws, maxb, sumb, 1);
  k_conv<3><<<1024, 256, 0, stream>>>(xT, b_c1, (const uint32_t*)(ws + P_WR1), cT);
  k_branch<3><<<4096, 256, 0, stream>>>(cT, ws, maxb, sumb, 0);
  k_conv<5><<<1024, 256, 0, stream>>>(xT, b_c2, (const uint32_t*)(ws + P_WR2), cT);
  k_branch<5><<<4096, 256, 0, stream>>>(cT, ws, maxb, sumb, 0);
  k_conv<7><<<1024, 256, 0, stream>>>(xT, b_c3, (const uint32_t*)(ws + P_WR3), cT);
  k_branch<7><<<4096, 256, 0, stream>>>(cT, ws, maxb, sumb, 0);

  k_tail<<<dim3(16, 16, 4), 256, 0, stream>>>(maxb, sumb, ws, cen, mas, w_out, b_out, out);
}